// Round 1
// baseline (424.506 us; speedup 1.0000x reference)
//
#include <hip/hip_runtime.h>

#define N_NODES 8192
#define D_IN    128
#define D_OUT   64

typedef __attribute__((ext_vector_type(8))) short short8;
typedef __attribute__((ext_vector_type(4))) float f32x4;

// fp32 -> bf16 bits, round-to-nearest-even
__device__ __forceinline__ short f2bf(float f) {
    unsigned u = __builtin_bit_cast(unsigned, f);
    u += 0x7fff + ((u >> 16) & 1);
    return (short)(u >> 16);
}

// ---------------- Kernel 1: dis[i] = rsqrt(rowsum(A[i,:])) ----------------
// One wave per row. 2048 blocks x 256 threads (4 waves). 256 MB streamed.
__global__ __launch_bounds__(256) void k_deg(const float* __restrict__ A,
                                             float* __restrict__ dis) {
    const int wave = threadIdx.x >> 6;
    const int lane = threadIdx.x & 63;
    const int row  = blockIdx.x * 4 + wave;
    const float4* Ar = (const float4*)(A + (size_t)row * N_NODES);
    float s = 0.f;
#pragma unroll
    for (int i = 0; i < 32; ++i) {
        float4 v = Ar[lane + 64 * i];
        s += (v.x + v.y) + (v.z + v.w);
    }
#pragma unroll
    for (int off = 32; off; off >>= 1) s += __shfl_down(s, off, 64);
    if (lane == 0) dis[row] = rsqrtf(s);
}

// ---------------- Kernel 2: G = (diag(dis) * X) @ W, packed in MFMA B-frag order
// Gp layout: [ktile t][ntile u][lane][j] bf16, where for G[k][n]:
//   t = k>>5, quad = (k>>3)&3, j = k&7, u = n>>4, lane = quad*16 + (n&15)
// One block per ktile (32 rows of X). 256 blocks x 256 threads.
__global__ __launch_bounds__(256) void k_gpack(const float* __restrict__ X,
                                               const float* __restrict__ W,
                                               const float* __restrict__ dis,
                                               unsigned short* __restrict__ Gp) {
    __shared__ float Wl[D_IN * D_OUT];     // 32 KB
    __shared__ float Xl[32 * 129];         // padded stride 129 (bank conflicts)
    const int t = blockIdx.x, tid = threadIdx.x;

    // stage W (8192 floats)
    const float4* W4 = (const float4*)W;
    float4* Wl4 = (float4*)Wl;
#pragma unroll
    for (int i = 0; i < 8; ++i) Wl4[tid + 256 * i] = W4[tid + 256 * i];
    // stage X tile (32 x 128 floats = 1024 float4)
    const float4* X4 = (const float4*)(X + (size_t)t * 32 * D_IN);
#pragma unroll
    for (int i = 0; i < 4; ++i) {
        int idx = tid + 256 * i;
        float4 v = X4[idx];
        int r = idx >> 5, c = (idx & 31) * 4;
        float* dst = Xl + r * 129 + c;
        dst[0] = v.x; dst[1] = v.y; dst[2] = v.z; dst[3] = v.w;
    }
    __syncthreads();

    const int kl = tid & 31;             // local k row 0..31
    const int nb = (tid >> 5) * 8;       // 8 consecutive n's
    float acc[8] = {0.f, 0.f, 0.f, 0.f, 0.f, 0.f, 0.f, 0.f};
    const float* xr = Xl + kl * 129;
    for (int d = 0; d < D_IN; ++d) {
        float xv = xr[d];
        const float* wr = Wl + d * D_OUT + nb;
#pragma unroll
        for (int c = 0; c < 8; ++c) acc[c] += xv * wr[c];
    }
    const float scale = dis[t * 32 + kl];
    const int quad = kl >> 3, j = kl & 7;
#pragma unroll
    for (int c = 0; c < 8; ++c) {
        int n = nb + c;
        int u = n >> 4;
        int lanei = quad * 16 + (n & 15);
        Gp[(((size_t)t * 4 + u) * 64 + lanei) * 8 + j] = (unsigned short)f2bf(acc[c] * scale);
    }
}

// ---------------- Kernel 3: h2 += A_chunk @ G  (bf16 MFMA, fp32 atomics) ----
// Block = 4 waves, each wave owns 16 rows x 64 cols. Grid (128 row-blocks, 8 K-splits).
__global__ __launch_bounds__(256) void k_spmm(const float* __restrict__ A,
                                              const unsigned short* __restrict__ Gp,
                                              float* __restrict__ h2) {
    const int lane = threadIdx.x & 63;
    const int wave = threadIdx.x >> 6;
    const int quad = lane >> 4;
    const int l15  = lane & 15;
    const int row  = blockIdx.x * 64 + wave * 16 + l15;
    const float* Ar = A + (size_t)row * N_NODES;
    const int kt0 = blockIdx.y * 32;     // 32 ktiles x 32 k = 1024 k per split

    f32x4 acc[4] = {};
    const short8* Gq = (const short8*)Gp;

    for (int kt = kt0; kt < kt0 + 32; ++kt) {
        const float4* pa = (const float4*)(Ar + kt * 32 + quad * 8);
        float4 a0 = pa[0], a1 = pa[1];
        short8 af;
        af[0] = f2bf(a0.x); af[1] = f2bf(a0.y); af[2] = f2bf(a0.z); af[3] = f2bf(a0.w);
        af[4] = f2bf(a1.x); af[5] = f2bf(a1.y); af[6] = f2bf(a1.z); af[7] = f2bf(a1.w);
        const short8* gb = Gq + (size_t)kt * 4 * 64 + lane;
#pragma unroll
        for (int u = 0; u < 4; ++u) {
            short8 bf = gb[u * 64];
            acc[u] = __builtin_amdgcn_mfma_f32_16x16x32_bf16(af, bf, acc[u], 0, 0, 0);
        }
    }
    // C/D layout: row = quad*4 + reg, col = lane&15 (guide §3, m89-verified)
#pragma unroll
    for (int u = 0; u < 4; ++u) {
#pragma unroll
        for (int r = 0; r < 4; ++r) {
            int orow = blockIdx.x * 64 + wave * 16 + quad * 4 + r;
            int ocol = u * 16 + l15;
            atomicAdd(&h2[(size_t)orow * D_OUT + ocol], acc[u][r]);
        }
    }
}

// ---------------- Kernel 4: out = relu(dis[i] * h2) ----------------
__global__ __launch_bounds__(256) void k_out(const float* __restrict__ h2,
                                             const float* __restrict__ dis,
                                             float* __restrict__ out) {
    int idx = blockIdx.x * 256 + threadIdx.x;   // float4 index, 131072 total
    float4 v = ((const float4*)h2)[idx];
    float s = dis[idx >> 4];                    // 16 float4 per row of 64
    float4 o;
    o.x = fmaxf(v.x * s, 0.f);
    o.y = fmaxf(v.y * s, 0.f);
    o.z = fmaxf(v.z * s, 0.f);
    o.w = fmaxf(v.w * s, 0.f);
    ((float4*)out)[idx] = o;
}

extern "C" void kernel_launch(void* const* d_in, const int* in_sizes, int n_in,
                              void* d_out, int out_size, void* d_ws, size_t ws_size,
                              hipStream_t stream) {
    const float* X = (const float*)d_in[0];   // features [8192,128]
    const float* A = (const float*)d_in[1];   // adjacency [8192,8192]
    const float* W = (const float*)d_in[2];   // weight [128,64]
    float* out = (float*)d_out;

    char* ws = (char*)d_ws;
    float*          dis = (float*)ws;                                  // 32 KB
    unsigned short* Gp  = (unsigned short*)(ws + 32768);               // 1 MB
    float*          h2  = (float*)(ws + 32768 + 1048576);              // 2 MB

    k_deg  <<<N_NODES / 4, 256, 0, stream>>>(A, dis);
    k_gpack<<<N_NODES / 32, 256, 0, stream>>>(X, W, dis, Gp);
    hipMemsetAsync(h2, 0, (size_t)N_NODES * D_OUT * sizeof(float), stream);
    k_spmm <<<dim3(N_NODES / 64, 8), 256, 0, stream>>>(A, Gp, h2);
    k_out  <<<(N_NODES * D_OUT / 4) / 256, 256, 0, stream>>>(h2, dis, out);
}